// Round 16
// baseline (551.101 us; speedup 1.0000x reference)
//
#include <hip/hip_runtime.h>

#define NODES 100000
#define EDGES 1600000
#define FEATS 128
#define NCLS  16
#define NGRP  ((NODES + 15) / 16)               // 6250 groups of 16 dst nodes

typedef unsigned int  u32;
typedef unsigned short u16;
typedef unsigned long long u64;
typedef __attribute__((ext_vector_type(8))) short short8;
typedef __attribute__((ext_vector_type(4))) float f32x4;

__device__ __forceinline__ float b2f(u16 v){ return __uint_as_float(((u32)v)<<16); }
__device__ __forceinline__ u16 f2b(float f){
  u32 u = __float_as_uint(f);
  u += 0x7fffu + ((u>>16)&1u);   // RNE
  return (u16)(u>>16);
}
__device__ __forceinline__ float blo(u32 p){ return __uint_as_float(p<<16); }
__device__ __forceinline__ float bhi(u32 p){ return __uint_as_float(p & 0xffff0000u); }

// global(16B) -> LDS, linear dest (wave-uniform base + lane*16), per-lane global src
__device__ __forceinline__ void gload16(const u16* g, u16* l){
  __builtin_amdgcn_global_load_lds(
      (const __attribute__((address_space(1))) u32*)g,
      (__attribute__((address_space(3))) u32*)l, 16, 0, 0);
}

// ---------------- lightweight atomic counting-sort partition ----------------
// ROUND 16: replaces the deterministic 3-phase partition (pA/scan/pC/csr,
// two heavy LDS-sort kernels over 19+13 MB) with zero+hist+scan+scatter.
// Within-node edge order becomes nondeterministic, which is safe: fagg's
// indicator-MFMA matches edges to rows via stored dstloc bits (order-free),
// and aggF2 only needs per-node contiguous ranges. Sum-order shift is
// within bf16 tolerance.

__global__ __launch_bounds__(256) void zero_k(int* __restrict__ a, int n){
  int i = blockIdx.x*256 + threadIdx.x;
  if (i < n) a[i] = 0;
}

__global__ __launch_bounds__(256) void hist_k(const int* __restrict__ dst,
                                              int* __restrict__ degs, int E){
  int e = blockIdx.x*256 + threadIdx.x;
  if (e < E) atomicAdd(&degs[dst[e]], 1);
}

// exclusive scan over n ints: 2048/block (8/thread)
__global__ __launch_bounds__(256) void scan1_k(const int* __restrict__ in, int* __restrict__ out,
                                               int* __restrict__ bsum, int n){
  __shared__ int sh[256];
  int t = threadIdx.x;
  int base = blockIdx.x*2048 + t*8;
  int v[8]; int s = 0;
  #pragma unroll
  for (int j=0;j<8;++j) v[j] = (base+j < n) ? in[base+j] : 0;
  #pragma unroll
  for (int j=0;j<8;++j){ int tmp = v[j]; v[j] = s; s += tmp; }
  sh[t] = s; __syncthreads();
  for (int off=1; off<256; off<<=1){
    int x = (t>=off) ? sh[t-off] : 0;
    __syncthreads();
    sh[t] += x;
    __syncthreads();
  }
  int excl = sh[t] - s;
  #pragma unroll
  for (int j=0;j<8;++j) if (base+j < n) out[base+j] = excl + v[j];
  if (t == 255) bsum[blockIdx.x] = sh[255];
}

// 256-entry block scan (nb <= 256)
__global__ __launch_bounds__(256) void scan2_k(const int* __restrict__ bsum,
                                               int* __restrict__ boff, int nb){
  __shared__ int sh[256];
  int t = threadIdx.x;
  int v = (t < nb) ? bsum[t] : 0;
  sh[t] = v; __syncthreads();
  for (int off=1; off<256; off<<=1){
    int x = (t>=off) ? sh[t-off] : 0;
    __syncthreads();
    sh[t] += x;
    __syncthreads();
  }
  if (t < nb) boff[t] = sh[t] - v;
}

// finalize: offs = gscan + boff; pos = offs (scatter cursors); invd
__global__ __launch_bounds__(256) void scan3n_k(const int* __restrict__ gscan,
    const int* __restrict__ boff, const int* __restrict__ degs,
    int* __restrict__ offs, int* __restrict__ pos, float* __restrict__ invd, int n){
  int i = blockIdx.x*256 + threadIdx.x;
  if (i < n){
    int v = gscan[i] + boff[i>>11];
    offs[i] = v; pos[i] = v;
    invd[i] = 1.f / fmaxf((float)degs[i], 1.f);
    if (i == 0) offs[n] = EDGES;
  }
}

// scatter: elist[pos[dst]++] = (dst&63)<<17 | src
__global__ __launch_bounds__(256) void scat_k(const int* __restrict__ src,
    const int* __restrict__ dst, int* __restrict__ pos, u32* __restrict__ elist, int E){
  int e = blockIdx.x*256 + threadIdx.x;
  if (e < E){
    int d = dst[e];
    int p = atomicAdd(&pos[d], 1);
    elist[p] = ((u32)(d & 63) << 17) | (u32)src[e];
  }
}

// ---------------- weight conversion: all four W -> Wt in ONE launch ----------
// W[K][N] row-major -> Wt[N][K] bf16. W0/W1/W2 are 128x128, W3 is 128x16.

__global__ __launch_bounds__(256) void convw4_k(const float* __restrict__ W0,
    const float* __restrict__ W1, const float* __restrict__ W2,
    const float* __restrict__ W3, u16* __restrict__ Wt0, u16* __restrict__ Wt1,
    u16* __restrict__ Wt2, u16* __restrict__ Wt3){
  int i = blockIdx.x*256 + threadIdx.x;
  if (i < 128*128){
    int k = i >> 7, n = i & 127;
    Wt0[n*128 + k] = f2b(W0[i]);
    Wt1[n*128 + k] = f2b(W1[i]);
    Wt2[n*128 + k] = f2b(W2[i]);
  }
  if (i < 128*16){
    int k = i >> 4, n = i & 15;
    Wt3[n*128 + k] = f2b(W3[i]);
  }
}

// ---------------- GEMM (layer 0 only): y[M x N] = h[M x 128] * W  ----------------
// Wt staged once per block into XOR-swizzled LDS (verified round 10: -22us).
// F32 flag: layer 0 reads feats as f32 and converts in-register with f2b
// (identical RNE rounding point to the old convf_k chain).

template<int NT, bool F32>
__global__ __launch_bounds__(256) void gemm_k(const void* __restrict__ hv,
                                              const u16* __restrict__ Wt,
                                              u16* __restrict__ y, int M){
  const int K = FEATS;
  const int N = NT*16;
  __shared__ __align__(128) u16 wbuf[NT*16*128];   // 32 KB (NT=8) / 4 KB (NT=1)
  int t = threadIdx.x;
  // cooperative staging: row n, col byte cb2 -> n*256 + (cb2 ^ ((n&7)<<4))
  #pragma unroll
  for (int i=0;i<NT;++i){
    int g16 = i*2048 + t*8;
    int n   = g16 >> 7;
    int cb2 = (g16 & 127) * 2;
    short8 wv = *(const short8*)(Wt + g16);
    *(short8*)((char*)wbuf + n*256 + (cb2 ^ ((n&7)<<4))) = wv;
  }
  __syncthreads();

  int lane = t & 63;
  int wave = t >> 6;
  int m    = lane & 15;
  int quad = lane >> 4;
  int row0 = (blockIdx.x*4 + wave)*16;
  if (row0 >= M) return;
  int rowA = row0 + m; if (rowA > M-1) rowA = M-1;

  f32x4 acc[NT];
  #pragma unroll
  for (int j=0;j<NT;++j) acc[j] = (f32x4){0.f,0.f,0.f,0.f};

  #pragma unroll
  for (int kb=0; kb<4; ++kb){
    short8 a;
    if constexpr (F32){
      const float* pa = (const float*)hv + (size_t)rowA*K + quad*8 + kb*32;
      float4 x0 = ((const float4*)pa)[0];
      float4 x1 = ((const float4*)pa)[1];
      union { u16 u[8]; short8 s; } au;
      au.u[0]=f2b(x0.x); au.u[1]=f2b(x0.y); au.u[2]=f2b(x0.z); au.u[3]=f2b(x0.w);
      au.u[4]=f2b(x1.x); au.u[5]=f2b(x1.y); au.u[6]=f2b(x1.z); au.u[7]=f2b(x1.w);
      a = au.s;
    } else {
      const u16* pa = (const u16*)hv + (size_t)rowA*K + quad*8 + kb*32;
      a = *(const short8*)pa;
    }
    #pragma unroll
    for (int j=0;j<NT;++j){
      // B[k][n] frag: row j*16+m, col bytes (kb*64 + quad*16) ^ ((m&7)<<4)
      short8 b = *(const short8*)((const char*)wbuf + (j*16+m)*256
                                  + ((kb*64 + quad*16) ^ ((m&7)<<4)));
      acc[j] = __builtin_amdgcn_mfma_f32_16x16x32_bf16(a, b, acc[j], 0, 0, 0);
    }
  }

  #pragma unroll
  for (int j=0;j<NT;++j){
    #pragma unroll
    for (int r=0;r<4;++r){
      int row = row0 + quad*4 + r;                  // C/D: row = quad*4 + reg
      if (row < M) y[(size_t)row*N + j*16 + m] = f2b(acc[j][r]);  // col = lane&15
    }
  }
}

// ---------------- fused MFMA aggregation + next-layer GEMM (layers 0..2) ----
// Round-12 verified structure (414us; best known).
// One wave per 16 dst nodes; single 8 KB gather buffer per wave.
// Wn staged in block-shared LDS (XOR-swizzled). Per 32-edge k-step:
//   gather 32 rows -> LDS 4x16 subtiles; indicator A-frag; tr_read B-frags;
//   8 MFMAs accumulate 16x128.
// Tail: h' = relu((1+eps)*y_self + inv*agg + b) -> LDS scratch -> in-register
// GEMM y_next = h' @ Wn with B from LDS. Numerically identical to gemm_k.

#define TRRD(dstv, lit) asm volatile("ds_read_b64_tr_b16 %0, %1 offset:" lit \
                                     : "=v"(dstv) : "v"(trb0))

template<int NTO>
__global__ __launch_bounds__(256) void fagg_k(const u16* __restrict__ y,
    const u32* __restrict__ el, const int* __restrict__ offs,
    const float* __restrict__ invd, const float* __restrict__ bias,
    const float* __restrict__ epsv, int ei,
    const u16* __restrict__ Wn,     // next-layer weights, [NTO*16][128] bf16
    u16* __restrict__ yout){        // y_next, row stride NTO*16
  __shared__ __align__(128) u16 ybuf[4][4096];       // 32 KB gather (8 KB/wave)
  __shared__ __align__(128) u16 wbuf[NTO*16*128];    // 32 KB (NTO=8) / 4 KB (NTO=1)
  int t = threadIdx.x;
  int lane = t & 63;
  int wave = t >> 6;
  int grp = blockIdx.x*4 + wave;
  bool valid = grp < NGRP;

  // ---- cooperative Wn staging into LDS (XOR-swizzled) ----
  #pragma unroll
  for (int i=0;i<NTO;++i){
    int g16 = i*2048 + t*8;
    int n   = g16 >> 7;
    int cb2 = (g16 & 127) * 2;
    short8 wv = *(const short8*)(Wn + g16);
    *(short8*)((char*)wbuf + n*256 + (cb2 ^ ((n&7)<<4))) = wv;
  }
  __syncthreads();
  if (!valid) return;

  int v0 = grp << 4;
  int m    = lane & 15;
  int quad = lane >> 4;
  int li   = lane & 31;
  u32 tgt = (u32)(((grp & 3) << 4) + m);   // this lane's A-row as dst&63 value

  u16* lb0 = &ybuf[wave][0];
  typedef __attribute__((address_space(3))) u16 lds_u16;
  u32 lbaddr = (u32)(size_t)(lds_u16*)lb0;
  // tr-read base: subtile row-block quad*2 (bytes quad*2048), column slot m*8.
  u32 trb0 = lbaddr + (u32)(quad*2048) + (u32)(m*8);

  // gather addressing: inst i, lane l fetches row 4i+((l&7)>>1),
  // u16 cols (l>>3)*16 + (l&1)*8 .. +8  -> lands at subtiled LDS slot l*16B
  int rsel = (lane & 7) >> 1;
  int gcol = ((lane >> 3) << 4) + ((lane & 1) << 3);

  int e0 = offs[v0];
  int e1 = offs[v0 + 16];
  int nstep = (e1 - e0 + 31) >> 5;

  f32x4 acc[8];
  #pragma unroll
  for (int cb=0;cb<8;++cb) acc[cb] = (f32x4){0.f,0.f,0.f,0.f};

  for (int st = 0; st < nstep; ++st){
    int idx = e0 + (st<<5) + li;
    u32 w = (idx < e1) ? el[idx] : 0xFFFE0000u;   // pad: dstloc=0x7FFF, src=0

    #pragma unroll
    for (int i=0;i<8;++i){
      u32 ws = (u32)__shfl((int)w, 4*i + rsel);
      int srow = (int)(ws & 0x1FFFFu);
      gload16(y + ((size_t)srow << 7) + gcol, lb0 + i*512);
    }

    // indicator A-fragment: lane holds A[m][quad*8+j], j=0..7 (bf16 1.0/0.0)
    union { u32 wv[4]; short8 s; } au;
    #pragma unroll
    for (int p=0;p<4;++p){
      u32 w0 = (u32)__shfl((int)w, quad*8 + 2*p);
      u32 w1 = (u32)__shfl((int)w, quad*8 + 2*p + 1);
      au.wv[p] = (((w0>>17) == tgt) ? 0x3F80u : 0u)
               | (((w1>>17) == tgt) ? 0x3F800000u : 0u);
    }

    asm volatile("s_waitcnt vmcnt(0)" ::: "memory");
    __builtin_amdgcn_sched_barrier(0);

    u64 tt[16];
    TRRD(tt[0],  "0");    TRRD(tt[1],  "1024");
    TRRD(tt[2],  "128");  TRRD(tt[3],  "1152");
    TRRD(tt[4],  "256");  TRRD(tt[5],  "1280");
    TRRD(tt[6],  "384");  TRRD(tt[7],  "1408");
    TRRD(tt[8],  "512");  TRRD(tt[9],  "1536");
    TRRD(tt[10], "640");  TRRD(tt[11], "1664");
    TRRD(tt[12], "768");  TRRD(tt[13], "1792");
    TRRD(tt[14], "896");  TRRD(tt[15], "1920");
    asm volatile("s_waitcnt lgkmcnt(0)" ::: "memory");
    __builtin_amdgcn_sched_barrier(0);

    #pragma unroll
    for (int cb=0;cb<8;++cb){
      union { u64 d[2]; short8 s; } bu;
      bu.d[0] = tt[2*cb]; bu.d[1] = tt[2*cb+1];
      acc[cb] = __builtin_amdgcn_mfma_f32_16x16x32_bf16(au.s, bu.s, acc[cb], 0, 0, 0);
    }
  }

  // ---- epilogue: h' = relu((1+eps)*y_self + inv*agg + b), into LDS scratch
  // h' C-layout: row quad*4+r, col cb*16+m. Scratch stride 136 u16 (272 B:
  // 16B-aligned rows for ds_read_b128, 2-way-conflict-free frag reads).
  float myinv = invd[v0 + m];
  float invr[4];
  #pragma unroll
  for (int r=0;r<4;++r) invr[r] = __shfl(myinv, quad*4 + r);
  float e1s = 1.f + epsv[ei];
  u16* zl = lb0;   // per-wave private; all tr_reads of the last step completed
  #pragma unroll
  for (int cb=0;cb<8;++cb){
    float bi = bias[cb*16 + m];
    #pragma unroll
    for (int r=0;r<4;++r){
      size_t off = (size_t)(v0 + quad*4 + r)*FEATS + cb*16 + m;
      float self = b2f(y[off]);
      float h = fmaxf(e1s*self + invr[r]*acc[cb][r] + bi, 0.f);
      zl[(quad*4 + r)*136 + cb*16 + m] = f2b(h);
    }
  }

  // ---- fused next-layer GEMM: yout = h' @ Wn  (A = h' from scratch, B = LDS Wn)
  short8 af[4];
  #pragma unroll
  for (int kb=0;kb<4;++kb)
    af[kb] = *(const short8*)(zl + m*136 + kb*32 + quad*8);

  #pragma unroll
  for (int nb=0;nb<NTO;++nb){
    f32x4 a2 = (f32x4){0.f,0.f,0.f,0.f};
    #pragma unroll
    for (int kb=0;kb<4;++kb){
      // B[k][n] frag: row nb*16+m, col bytes (kb*64 + quad*16) ^ ((m&7)<<4)
      short8 bf = *(const short8*)((const char*)wbuf + (nb*16+m)*256
                                   + ((kb*64 + quad*16) ^ ((m&7)<<4)));
      a2 = __builtin_amdgcn_mfma_f32_16x16x32_bf16(af[kb], bf, a2, 0, 0, 0);
    }
    #pragma unroll
    for (int r=0;r<4;++r)
      yout[(size_t)(v0 + quad*4 + r)*(NTO*16) + nb*16 + m] = f2b(a2[r]);
  }
}

// ---------------- final 16-feat aggregation, f32 out, no relu ----------------
// 8 edges in parallel (sub = lane>>3), u32 loads (2 feats per lane).

__global__ __launch_bounds__(256) void aggF2_k(const u16* __restrict__ y,
    const u32* __restrict__ el, const int* __restrict__ offs,
    const int* __restrict__ degs, const float* __restrict__ invd,
    const float* __restrict__ bias, const float* __restrict__ epsv,
    float* __restrict__ out, int M){
  int lane = threadIdx.x & 63;
  int v = blockIdx.x*4 + (threadIdx.x >> 6);
  if (v >= M) return;
  int sub = lane >> 3;        // edge slot 0..7
  int f2  = lane & 7;         // feats 2f2, 2f2+1
  const u32* y2 = (const u32*)y;   // row stride = 8 u32
  int start = offs[v], deg = degs[v];
  float acc0 = 0.f, acc1 = 0.f;
  for (int e = sub; e < deg; e += 8){
    u32 s = el[start + e] & 0x1FFFFu;
    u32 p = y2[(size_t)s*8 + f2];
    acc0 += blo(p); acc1 += bhi(p);
  }
  acc0 += __shfl_xor(acc0, 8);  acc1 += __shfl_xor(acc1, 8);
  acc0 += __shfl_xor(acc0, 16); acc1 += __shfl_xor(acc1, 16);
  acc0 += __shfl_xor(acc0, 32); acc1 += __shfl_xor(acc1, 32);
  if (sub == 0){
    u32 pv = y2[(size_t)v*8 + f2];
    float2 bi = ((const float2*)bias)[f2];
    float e1s = 1.f + epsv[3];
    float inv = invd[v];
    out[(size_t)v*NCLS + 2*f2    ] = e1s*blo(pv) + inv*acc0 + bi.x;
    out[(size_t)v*NCLS + 2*f2 + 1] = e1s*bhi(pv) + inv*acc1 + bi.y;
  }
}

// ---------------- launch ----------------

extern "C" void kernel_launch(void* const* d_in, const int* in_sizes, int n_in,
                              void* d_out, int out_size, void* d_ws, size_t ws_size,
                              hipStream_t stream){
  const float* feats = (const float*)d_in[0];
  const int*   src   = (const int*)d_in[1];
  const int*   dst   = (const int*)d_in[2];
  const float* W0 = (const float*)d_in[3];  const float* b0 = (const float*)d_in[4];
  const float* W1 = (const float*)d_in[5];  const float* b1 = (const float*)d_in[6];
  const float* W2 = (const float*)d_in[7];  const float* b2 = (const float*)d_in[8];
  const float* W3 = (const float*)d_in[9];  const float* b3 = (const float*)d_in[10];
  const float* eps = (const float*)d_in[11];

  char* w = (char*)d_ws;
  auto alloc = [&](size_t bytes)->char*{
    char* p = w; w += (bytes + 255) & ~(size_t)255; return p;
  };
  int*  degs  = (int*)alloc(sizeof(int)*NODES);
  int*  gscan = (int*)alloc(sizeof(int)*NODES);
  int*  bsum  = (int*)alloc(sizeof(int)*256);
  int*  boff  = (int*)alloc(sizeof(int)*256);
  int*  offs  = (int*)alloc(sizeof(int)*(NODES+1));
  int*  pos   = (int*)alloc(sizeof(int)*NODES);
  float* invd = (float*)alloc(sizeof(float)*NODES);
  u32*  elist = (u32*)alloc(sizeof(u32)*EDGES);
  u16*  hb    = (u16*)alloc(sizeof(u16)*(size_t)NODES*FEATS);
  u16*  yb    = (u16*)alloc(sizeof(u16)*(size_t)NODES*FEATS);
  u16*  Wt0   = (u16*)alloc(sizeof(u16)*128*128);
  u16*  Wt1   = (u16*)alloc(sizeof(u16)*128*128);
  u16*  Wt2   = (u16*)alloc(sizeof(u16)*128*128);
  u16*  Wt3   = (u16*)alloc(sizeof(u16)*16*128);

  int eblocks = (EDGES + 255)/256;               // 6250
  int nblocks = (NODES + 255)/256;               // 391
  int snb     = (NODES + 2047)/2048;             // 49 <= 256

  // ---- atomic counting-sort partition -> per-node contiguous elist ----
  zero_k<<<nblocks, 256, 0, stream>>>(degs, NODES);
  hist_k<<<eblocks, 256, 0, stream>>>(dst, degs, EDGES);
  scan1_k<<<snb, 256, 0, stream>>>(degs, gscan, bsum, NODES);
  scan2_k<<<1, 256, 0, stream>>>(bsum, boff, snb);
  scan3n_k<<<nblocks, 256, 0, stream>>>(gscan, boff, degs, offs, pos, invd, NODES);
  scat_k<<<eblocks, 256, 0, stream>>>(src, dst, pos, elist, EDGES);

  // ---- convert weights (one launch) ----
  convw4_k<<<(128*128+255)/256, 256, 0, stream>>>(W0, W1, W2, W3, Wt0, Wt1, Wt2, Wt3);

  int gblocks = (NODES + 63)/64;
  int mblocks = (NGRP + 3)/4;
  int ablocks = (NODES + 3)/4;

  // layer 0 GEMM: y0 = f2b(feats)@W0  (f32 input, in-register conversion)
  gemm_k<8, true><<<gblocks, 256, 0, stream>>>(feats, Wt0, yb, NODES);
  // fused: h1 = relu((1+e0)y0 + mean(y0) + b0); y1 = h1@W1   (yb -> hb)
  fagg_k<8><<<mblocks, 256, 0, stream>>>(yb, elist, offs, invd, b0, eps, 0, Wt1, hb);
  // fused: h2 = relu((1+e1)y1 + mean(y1) + b1); y2 = h2@W2   (hb -> yb)
  fagg_k<8><<<mblocks, 256, 0, stream>>>(hb, elist, offs, invd, b1, eps, 1, Wt2, yb);
  // fused: h3 = relu((1+e2)y2 + mean(y2) + b2); y3 = h3@W3   (yb -> hb, 16 cols)
  fagg_k<1><<<mblocks, 256, 0, stream>>>(yb, elist, offs, invd, b2, eps, 2, Wt3, hb);
  // layer 3 epilogue: out = (1+e3)y3 + mean(y3) + b3  (f32, no relu)
  aggF2_k<<<ablocks, 256, 0, stream>>>(hb, elist, offs, degs, invd, b3, eps, (float*)d_out, NODES);
}

// Round 17
// 411.187 us; speedup vs baseline: 1.3403x; 1.3403x over previous
//
#include <hip/hip_runtime.h>

#define NODES 100000
#define EDGES 1600000
#define FEATS 128
#define NCLS  16

// bucket = 64 consecutive dst nodes
#define BSH    6
#define BNODES 64
#define NB     ((NODES + BNODES - 1) / BNODES)   // 1563
#define CHUNK  8192
#define NBLK   ((EDGES + CHUNK - 1) / CHUNK)     // 196
#define NHIST  (NB * NBLK)                       // 306348
#define BCAP   2048                              // per-bucket LDS sort capacity
#define NGRP   ((NODES + 15) / 16)               // 6250 groups of 16 dst nodes

typedef unsigned int  u32;
typedef unsigned short u16;
typedef unsigned long long u64;
typedef __attribute__((ext_vector_type(8))) short short8;
typedef __attribute__((ext_vector_type(4))) float f32x4;

__device__ __forceinline__ float b2f(u16 v){ return __uint_as_float(((u32)v)<<16); }
__device__ __forceinline__ u16 f2b(float f){
  u32 u = __float_as_uint(f);
  u += 0x7fffu + ((u>>16)&1u);   // RNE
  return (u16)(u>>16);
}
__device__ __forceinline__ float blo(u32 p){ return __uint_as_float(p<<16); }
__device__ __forceinline__ float bhi(u32 p){ return __uint_as_float(p & 0xffff0000u); }

// global(16B) -> LDS, linear dest (wave-uniform base + lane*16), per-lane global src
__device__ __forceinline__ void gload16(const u16* g, u16* l){
  __builtin_amdgcn_global_load_lds(
      (const __attribute__((address_space(1))) u32*)g,
      (__attribute__((address_space(3))) u32*)l, 16, 0, 0);
}

// ---------------- phase A: per-chunk bucket histogram ----------------

__global__ __launch_bounds__(256) void pA_k(const int* __restrict__ dst,
                                            int* __restrict__ gh, int E){
  __shared__ int hist[NB];
  int t = threadIdx.x, blk = blockIdx.x;
  for (int j = t; j < NB; j += 256) hist[j] = 0;
  __syncthreads();
  int e0 = blk*CHUNK, e1 = e0 + CHUNK; if (e1 > E) e1 = E;
  for (int e = e0 + t; e < e1; e += 256) atomicAdd(&hist[dst[e] >> BSH], 1);
  __syncthreads();
  for (int j = t; j < NB; j += 256) gh[j*NBLK + blk] = hist[j];
}

// ---------------- phase B: exclusive scan of gh ----------------

__global__ __launch_bounds__(256) void scan1_k(const int* __restrict__ in, int* __restrict__ out,
                                               int* __restrict__ bsum, int n){
  __shared__ int sh[256];
  int t = threadIdx.x;
  int base = blockIdx.x*2048 + t*8;
  int v[8]; int s = 0;
  #pragma unroll
  for (int j=0;j<8;++j) v[j] = (base+j < n) ? in[base+j] : 0;
  #pragma unroll
  for (int j=0;j<8;++j){ int tmp = v[j]; v[j] = s; s += tmp; }
  sh[t] = s; __syncthreads();
  for (int off=1; off<256; off<<=1){
    int x = (t>=off) ? sh[t-off] : 0;
    __syncthreads();
    sh[t] += x;
    __syncthreads();
  }
  int excl = sh[t] - s;
  #pragma unroll
  for (int j=0;j<8;++j) if (base+j < n) out[base+j] = excl + v[j];
  if (t == 255) bsum[blockIdx.x] = sh[255];
}

// 256-entry block scan (nb <= 256)
__global__ __launch_bounds__(256) void scan2_k(const int* __restrict__ bsum,
                                               int* __restrict__ boff, int nb){
  __shared__ int sh[256];
  int t = threadIdx.x;
  int v = (t < nb) ? bsum[t] : 0;
  sh[t] = v; __syncthreads();
  for (int off=1; off<256; off<<=1){
    int x = (t>=off) ? sh[t-off] : 0;
    __syncthreads();
    sh[t] += x;
    __syncthreads();
  }
  if (t < nb) boff[t] = sh[t] - v;
}

__global__ void scan3_k(int* __restrict__ gscan, const int* __restrict__ boff,
                        int* __restrict__ bstart, int n){
  int i = blockIdx.x*256 + threadIdx.x;
  if (i < n){
    int v = gscan[i] + boff[i>>11];
    gscan[i] = v;
    if (i % NBLK == 0) bstart[i / NBLK] = v;
    if (i == 0) bstart[NB] = EDGES;
  }
}

// ---------------- phase C: LDS counting sort, then streamed coalesced write ----------------
// packed word: (dst & 63) << 17 | src
// NOTE (round-16 lesson): this chunked LDS sort exists to make the elist
// writes COALESCED. A naive atomic scatter measured 120us/dispatch with
// 105MB WRITE_SIZE (16x partial-line write amplification). Do not replace.

__global__ __launch_bounds__(256) void pC_k(const int* __restrict__ src,
    const int* __restrict__ dst, const int* __restrict__ gscan,
    u32* __restrict__ elist, int E){
  __shared__ int A[NB];        // hist -> excl -> delta
  __shared__ int B[NB];        // running local position (starts at excl)
  __shared__ int sp[256];      // scan partials
  __shared__ u32 pay[CHUNK];   // payload by local sorted index
  __shared__ u16 bkt[CHUNK];   // bucket by local sorted index
  int t = threadIdx.x, blk = blockIdx.x;
  for (int j = t; j < NB; j += 256) A[j] = 0;
  __syncthreads();
  int e0 = blk*CHUNK, e1 = e0 + CHUNK; if (e1 > E) e1 = E;
  int cnt = e1 - e0;
  for (int e = e0 + t; e < e1; e += 256) atomicAdd(&A[dst[e] >> BSH], 1);
  __syncthreads();
  // block-exclusive scan over A[0..NB): 7 elems/thread
  {
    int base = t*7;
    int cv[7]; int s = 0;
    #pragma unroll
    for (int j=0;j<7;++j){ int idx = base+j; cv[j] = (idx < NB) ? A[idx] : 0; s += cv[j]; }
    sp[t] = s; __syncthreads();
    for (int off=1; off<256; off<<=1){
      int x = (t>=off) ? sp[t-off] : 0;
      __syncthreads();
      sp[t] += x;
      __syncthreads();
    }
    int run = sp[t] - s;
    #pragma unroll
    for (int j=0;j<7;++j){
      int idx = base+j;
      if (idx < NB){ A[idx] = run; B[idx] = run; run += cv[j]; }
    }
  }
  __syncthreads();
  // delta[b] = global run start - local excl
  for (int j = t; j < NB; j += 256) A[j] = gscan[j*NBLK + blk] - A[j];
  __syncthreads();
  // placement into LDS sorted order
  for (int e = e0 + t; e < e1; e += 256){
    int d = dst[e];
    int b = d >> BSH;
    u32 w = ((u32)(d & (BNODES-1)) << 17) | (u32)src[e];
    int r = atomicAdd(&B[b], 1);
    pay[r] = w; bkt[r] = (u16)b;
  }
  __syncthreads();
  // streamed write: consecutive i -> consecutive global slots within runs
  for (int i = t; i < cnt; i += 256){
    int b = bkt[i];
    elist[i + A[b]] = pay[i];
  }
}

// ---------------- per-bucket counting sort (in place) + degrees ----------------
// NOTE: keeps the full packed word (dstloc<<17 | src) in elist.

__global__ __launch_bounds__(256) void csr_k(u32* __restrict__ elist,
    const int* __restrict__ bstart, int* __restrict__ offs, int* __restrict__ degs,
    float* __restrict__ invd, int M){
  __shared__ int hist[BNODES];
  __shared__ int pos[BNODES];
  __shared__ u32 buf[BCAP];
  __shared__ u32 buf2[BCAP];
  int b = blockIdx.x, t = threadIdx.x;
  if (b == 0 && t == 0) offs[M] = EDGES;     // sentinel for group ranges
  if (t < BNODES) hist[t] = 0;
  __syncthreads();
  int s0 = bstart[b];
  int cnt = bstart[b+1] - s0; if (cnt > BCAP) cnt = BCAP;
  u32* el = elist + s0;
  for (int e = t; e < cnt; e += 256){
    u32 w = el[e];
    buf[e] = w;
    atomicAdd(&hist[w>>17], 1);
  }
  __syncthreads();
  if (t < BNODES){                      // single-wave exclusive scan
    int v = hist[t];
    int s = v;
    for (int off = 1; off < BNODES; off <<= 1){
      int x = __shfl_up(s, off);
      if (t >= off) s += x;
    }
    int excl = s - v;
    pos[t] = excl;
    int node = b*BNODES + t;
    if (node < M){
      offs[node] = s0 + excl;
      degs[node] = v;
      invd[node] = 1.f / fmaxf((float)v, 1.f);
    }
  }
  __syncthreads();
  for (int e = t; e < cnt; e += 256){
    u32 w = buf[e];
    int p = atomicAdd(&pos[w>>17], 1);
    buf2[p] = w;                        // keep dstloc bits for MFMA aggregation
  }
  __syncthreads();
  for (int e = t; e < cnt; e += 256) el[e] = buf2[e];   // coalesced write-back
}

// ---------------- weight conversion: all four W -> Wt in ONE launch ----------
// W[K][N] row-major -> Wt[N][K] bf16. W0/W1/W2 are 128x128, W3 is 128x16.

__global__ __launch_bounds__(256) void convw4_k(const float* __restrict__ W0,
    const float* __restrict__ W1, const float* __restrict__ W2,
    const float* __restrict__ W3, u16* __restrict__ Wt0, u16* __restrict__ Wt1,
    u16* __restrict__ Wt2, u16* __restrict__ Wt3){
  int i = blockIdx.x*256 + threadIdx.x;
  if (i < 128*128){
    int k = i >> 7, n = i & 127;
    Wt0[n*128 + k] = f2b(W0[i]);
    Wt1[n*128 + k] = f2b(W1[i]);
    Wt2[n*128 + k] = f2b(W2[i]);
  }
  if (i < 128*16){
    int k = i >> 4, n = i & 15;
    Wt3[n*128 + k] = f2b(W3[i]);
  }
}

// ---------------- GEMM (layer 0 only): y[M x N] = h[M x 128] * W  ----------------
// Wt staged once per block into XOR-swizzled LDS (verified round 10: -22us).
// F32 flag: layer 0 reads feats as f32 and converts in-register with f2b
// (identical RNE rounding point to the old convf_k chain).

template<int NT, bool F32>
__global__ __launch_bounds__(256) void gemm_k(const void* __restrict__ hv,
                                              const u16* __restrict__ Wt,
                                              u16* __restrict__ y, int M){
  const int K = FEATS;
  const int N = NT*16;
  __shared__ __align__(128) u16 wbuf[NT*16*128];   // 32 KB (NT=8) / 4 KB (NT=1)
  int t = threadIdx.x;
  // cooperative staging: row n, col byte cb2 -> n*256 + (cb2 ^ ((n&7)<<4))
  #pragma unroll
  for (int i=0;i<NT;++i){
    int g16 = i*2048 + t*8;
    int n   = g16 >> 7;
    int cb2 = (g16 & 127) * 2;
    short8 wv = *(const short8*)(Wt + g16);
    *(short8*)((char*)wbuf + n*256 + (cb2 ^ ((n&7)<<4))) = wv;
  }
  __syncthreads();

  int lane = t & 63;
  int wave = t >> 6;
  int m    = lane & 15;
  int quad = lane >> 4;
  int row0 = (blockIdx.x*4 + wave)*16;
  if (row0 >= M) return;
  int rowA = row0 + m; if (rowA > M-1) rowA = M-1;

  f32x4 acc[NT];
  #pragma unroll
  for (int j=0;j<NT;++j) acc[j] = (f32x4){0.f,0.f,0.f,0.f};

  #pragma unroll
  for (int kb=0; kb<4; ++kb){
    short8 a;
    if constexpr (F32){
      const float* pa = (const float*)hv + (size_t)rowA*K + quad*8 + kb*32;
      float4 x0 = ((const float4*)pa)[0];
      float4 x1 = ((const float4*)pa)[1];
      union { u16 u[8]; short8 s; } au;
      au.u[0]=f2b(x0.x); au.u[1]=f2b(x0.y); au.u[2]=f2b(x0.z); au.u[3]=f2b(x0.w);
      au.u[4]=f2b(x1.x); au.u[5]=f2b(x1.y); au.u[6]=f2b(x1.z); au.u[7]=f2b(x1.w);
      a = au.s;
    } else {
      const u16* pa = (const u16*)hv + (size_t)rowA*K + quad*8 + kb*32;
      a = *(const short8*)pa;
    }
    #pragma unroll
    for (int j=0;j<NT;++j){
      // B[k][n] frag: row j*16+m, col bytes (kb*64 + quad*16) ^ ((m&7)<<4)
      short8 b = *(const short8*)((const char*)wbuf + (j*16+m)*256
                                  + ((kb*64 + quad*16) ^ ((m&7)<<4)));
      acc[j] = __builtin_amdgcn_mfma_f32_16x16x32_bf16(a, b, acc[j], 0, 0, 0);
    }
  }

  #pragma unroll
  for (int j=0;j<NT;++j){
    #pragma unroll
    for (int r=0;r<4;++r){
      int row = row0 + quad*4 + r;                  // C/D: row = quad*4 + reg
      if (row < M) y[(size_t)row*N + j*16 + m] = f2b(acc[j][r]);  // col = lane&15
    }
  }
}

// ---------------- fused MFMA aggregation + next-layer GEMM (layers 0..2) ----
// Round-12/15 verified structure (412.5us; session best).
// One wave per 16 dst nodes; single 8 KB gather buffer per wave.
// Wn staged in block-shared LDS (XOR-swizzled). Per 32-edge k-step:
//   gather 32 rows -> LDS 4x16 subtiles; indicator A-frag; tr_read B-frags;
//   8 MFMAs accumulate 16x128.
// Tail: h' = relu((1+eps)*y_self + inv*agg + b) -> LDS scratch -> in-register
// GEMM y_next = h' @ Wn with B from LDS. Numerically identical to gemm_k.

#define TRRD(dstv, lit) asm volatile("ds_read_b64_tr_b16 %0, %1 offset:" lit \
                                     : "=v"(dstv) : "v"(trb0))

template<int NTO>
__global__ __launch_bounds__(256) void fagg_k(const u16* __restrict__ y,
    const u32* __restrict__ el, const int* __restrict__ offs,
    const float* __restrict__ invd, const float* __restrict__ bias,
    const float* __restrict__ epsv, int ei,
    const u16* __restrict__ Wn,     // next-layer weights, [NTO*16][128] bf16
    u16* __restrict__ yout){        // y_next, row stride NTO*16
  __shared__ __align__(128) u16 ybuf[4][4096];       // 32 KB gather (8 KB/wave)
  __shared__ __align__(128) u16 wbuf[NTO*16*128];    // 32 KB (NTO=8) / 4 KB (NTO=1)
  int t = threadIdx.x;
  int lane = t & 63;
  int wave = t >> 6;
  int grp = blockIdx.x*4 + wave;
  bool valid = grp < NGRP;

  // ---- cooperative Wn staging into LDS (XOR-swizzled) ----
  #pragma unroll
  for (int i=0;i<NTO;++i){
    int g16 = i*2048 + t*8;
    int n   = g16 >> 7;
    int cb2 = (g16 & 127) * 2;
    short8 wv = *(const short8*)(Wn + g16);
    *(short8*)((char*)wbuf + n*256 + (cb2 ^ ((n&7)<<4))) = wv;
  }
  __syncthreads();
  if (!valid) return;

  int v0 = grp << 4;
  int m    = lane & 15;
  int quad = lane >> 4;
  int li   = lane & 31;
  u32 tgt = (u32)(((grp & 3) << 4) + m);   // this lane's A-row as dst&63 value

  u16* lb0 = &ybuf[wave][0];
  typedef __attribute__((address_space(3))) u16 lds_u16;
  u32 lbaddr = (u32)(size_t)(lds_u16*)lb0;
  // tr-read base: subtile row-block quad*2 (bytes quad*2048), column slot m*8.
  u32 trb0 = lbaddr + (u32)(quad*2048) + (u32)(m*8);

  // gather addressing: inst i, lane l fetches row 4i+((l&7)>>1),
  // u16 cols (l>>3)*16 + (l&1)*8 .. +8  -> lands at subtiled LDS slot l*16B
  int rsel = (lane & 7) >> 1;
  int gcol = ((lane >> 3) << 4) + ((lane & 1) << 3);

  int e0 = offs[v0];
  int e1 = offs[v0 + 16];
  int nstep = (e1 - e0 + 31) >> 5;

  f32x4 acc[8];
  #pragma unroll
  for (int cb=0;cb<8;++cb) acc[cb] = (f32x4){0.f,0.f,0.f,0.f};

  for (int st = 0; st < nstep; ++st){
    int idx = e0 + (st<<5) + li;
    u32 w = (idx < e1) ? el[idx] : 0xFFFE0000u;   // pad: dstloc=0x7FFF, src=0

    #pragma unroll
    for (int i=0;i<8;++i){
      u32 ws = (u32)__shfl((int)w, 4*i + rsel);
      int srow = (int)(ws & 0x1FFFFu);
      gload16(y + ((size_t)srow << 7) + gcol, lb0 + i*512);
    }

    // indicator A-fragment: lane holds A[m][quad*8+j], j=0..7 (bf16 1.0/0.0)
    union { u32 wv[4]; short8 s; } au;
    #pragma unroll
    for (int p=0;p<4;++p){
      u32 w0 = (u32)__shfl((int)w, quad*8 + 2*p);
      u32 w1 = (u32)__shfl((int)w, quad*8 + 2*p + 1);
      au.wv[p] = (((w0>>17) == tgt) ? 0x3F80u : 0u)
               | (((w1>>17) == tgt) ? 0x3F800000u : 0u);
    }

    asm volatile("s_waitcnt vmcnt(0)" ::: "memory");
    __builtin_amdgcn_sched_barrier(0);

    u64 tt[16];
    TRRD(tt[0],  "0");    TRRD(tt[1],  "1024");
    TRRD(tt[2],  "128");  TRRD(tt[3],  "1152");
    TRRD(tt[4],  "256");  TRRD(tt[5],  "1280");
    TRRD(tt[6],  "384");  TRRD(tt[7],  "1408");
    TRRD(tt[8],  "512");  TRRD(tt[9],  "1536");
    TRRD(tt[10], "640");  TRRD(tt[11], "1664");
    TRRD(tt[12], "768");  TRRD(tt[13], "1792");
    TRRD(tt[14], "896");  TRRD(tt[15], "1920");
    asm volatile("s_waitcnt lgkmcnt(0)" ::: "memory");
    __builtin_amdgcn_sched_barrier(0);

    #pragma unroll
    for (int cb=0;cb<8;++cb){
      union { u64 d[2]; short8 s; } bu;
      bu.d[0] = tt[2*cb]; bu.d[1] = tt[2*cb+1];
      acc[cb] = __builtin_amdgcn_mfma_f32_16x16x32_bf16(au.s, bu.s, acc[cb], 0, 0, 0);
    }
  }

  // ---- epilogue: h' = relu((1+eps)*y_self + inv*agg + b), into LDS scratch
  // h' C-layout: row quad*4+r, col cb*16+m. Scratch stride 136 u16 (272 B:
  // 16B-aligned rows for ds_read_b128, 2-way-conflict-free frag reads).
  float myinv = invd[v0 + m];
  float invr[4];
  #pragma unroll
  for (int r=0;r<4;++r) invr[r] = __shfl(myinv, quad*4 + r);
  float e1s = 1.f + epsv[ei];
  u16* zl = lb0;   // per-wave private; all tr_reads of the last step completed
  #pragma unroll
  for (int cb=0;cb<8;++cb){
    float bi = bias[cb*16 + m];
    #pragma unroll
    for (int r=0;r<4;++r){
      size_t off = (size_t)(v0 + quad*4 + r)*FEATS + cb*16 + m;
      float self = b2f(y[off]);
      float h = fmaxf(e1s*self + invr[r]*acc[cb][r] + bi, 0.f);
      zl[(quad*4 + r)*136 + cb*16 + m] = f2b(h);
    }
  }

  // ---- fused next-layer GEMM: yout = h' @ Wn  (A = h' from scratch, B = LDS Wn)
  short8 af[4];
  #pragma unroll
  for (int kb=0;kb<4;++kb)
    af[kb] = *(const short8*)(zl + m*136 + kb*32 + quad*8);

  #pragma unroll
  for (int nb=0;nb<NTO;++nb){
    f32x4 a2 = (f32x4){0.f,0.f,0.f,0.f};
    #pragma unroll
    for (int kb=0;kb<4;++kb){
      // B[k][n] frag: row nb*16+m, col bytes (kb*64 + quad*16) ^ ((m&7)<<4)
      short8 bf = *(const short8*)((const char*)wbuf + (nb*16+m)*256
                                   + ((kb*64 + quad*16) ^ ((m&7)<<4)));
      a2 = __builtin_amdgcn_mfma_f32_16x16x32_bf16(af[kb], bf, a2, 0, 0, 0);
    }
    #pragma unroll
    for (int r=0;r<4;++r)
      yout[(size_t)(v0 + quad*4 + r)*(NTO*16) + nb*16 + m] = f2b(a2[r]);
  }
}

// ---------------- final 16-feat aggregation, f32 out, no relu ----------------
// 8 edges in parallel (sub = lane>>3), u32 loads (2 feats per lane).

__global__ __launch_bounds__(256) void aggF2_k(const u16* __restrict__ y,
    const u32* __restrict__ el, const int* __restrict__ offs,
    const int* __restrict__ degs, const float* __restrict__ invd,
    const float* __restrict__ bias, const float* __restrict__ epsv,
    float* __restrict__ out, int M){
  int lane = threadIdx.x & 63;
  int v = blockIdx.x*4 + (threadIdx.x >> 6);
  if (v >= M) return;
  int sub = lane >> 3;        // edge slot 0..7
  int f2  = lane & 7;         // feats 2f2, 2f2+1
  const u32* y2 = (const u32*)y;   // row stride = 8 u32
  int start = offs[v], deg = degs[v];
  float acc0 = 0.f, acc1 = 0.f;
  for (int e = sub; e < deg; e += 8){
    u32 s = el[start + e] & 0x1FFFFu;
    u32 p = y2[(size_t)s*8 + f2];
    acc0 += blo(p); acc1 += bhi(p);
  }
  acc0 += __shfl_xor(acc0, 8);  acc1 += __shfl_xor(acc1, 8);
  acc0 += __shfl_xor(acc0, 16); acc1 += __shfl_xor(acc1, 16);
  acc0 += __shfl_xor(acc0, 32); acc1 += __shfl_xor(acc1, 32);
  if (sub == 0){
    u32 pv = y2[(size_t)v*8 + f2];
    float2 bi = ((const float2*)bias)[f2];
    float e1s = 1.f + epsv[3];
    float inv = invd[v];
    out[(size_t)v*NCLS + 2*f2    ] = e1s*blo(pv) + inv*acc0 + bi.x;
    out[(size_t)v*NCLS + 2*f2 + 1] = e1s*bhi(pv) + inv*acc1 + bi.y;
  }
}

// ---------------- launch ----------------

extern "C" void kernel_launch(void* const* d_in, const int* in_sizes, int n_in,
                              void* d_out, int out_size, void* d_ws, size_t ws_size,
                              hipStream_t stream){
  const float* feats = (const float*)d_in[0];
  const int*   src   = (const int*)d_in[1];
  const int*   dst   = (const int*)d_in[2];
  const float* W0 = (const float*)d_in[3];  const float* b0 = (const float*)d_in[4];
  const float* W1 = (const float*)d_in[5];  const float* b1 = (const float*)d_in[6];
  const float* W2 = (const float*)d_in[7];  const float* b2 = (const float*)d_in[8];
  const float* W3 = (const float*)d_in[9];  const float* b3 = (const float*)d_in[10];
  const float* eps = (const float*)d_in[11];

  char* w = (char*)d_ws;
  auto alloc = [&](size_t bytes)->char*{
    char* p = w; w += (bytes + 255) & ~(size_t)255; return p;
  };
  int*  gh    = (int*)alloc(sizeof(int)*NHIST);
  int*  gscan = (int*)alloc(sizeof(int)*NHIST);
  int*  bsum  = (int*)alloc(sizeof(int)*256);
  int*  boff  = (int*)alloc(sizeof(int)*256);
  int*  bstart= (int*)alloc(sizeof(int)*(NB+1));
  int*  offs  = (int*)alloc(sizeof(int)*(NODES+1));
  int*  degs  = (int*)alloc(sizeof(int)*NODES);
  float* invd = (float*)alloc(sizeof(float)*NODES);
  u32*  elist = (u32*)alloc(sizeof(u32)*EDGES);
  u16*  hb    = (u16*)alloc(sizeof(u16)*(size_t)NODES*FEATS);
  u16*  yb    = (u16*)alloc(sizeof(u16)*(size_t)NODES*FEATS);
  u16*  Wt0   = (u16*)alloc(sizeof(u16)*128*128);
  u16*  Wt1   = (u16*)alloc(sizeof(u16)*128*128);
  u16*  Wt2   = (u16*)alloc(sizeof(u16)*128*128);
  u16*  Wt3   = (u16*)alloc(sizeof(u16)*16*128);

  // ---- deterministic 3-phase partition -> dense bucketed elist ----
  pA_k<<<NBLK, 256, 0, stream>>>(dst, gh, EDGES);
  int snb = (NHIST + 2047)/2048;                 // 150 <= 256
  scan1_k<<<snb, 256, 0, stream>>>(gh, gscan, bsum, NHIST);
  scan2_k<<<1, 256, 0, stream>>>(bsum, boff, snb);
  scan3_k<<<(NHIST+255)/256, 256, 0, stream>>>(gscan, boff, bstart, NHIST);
  pC_k<<<NBLK, 256, 0, stream>>>(src, dst, gscan, elist, EDGES);
  csr_k<<<NB, 256, 0, stream>>>(elist, bstart, offs, degs, invd, NODES);

  // ---- convert weights (one launch) ----
  convw4_k<<<(128*128+255)/256, 256, 0, stream>>>(W0, W1, W2, W3, Wt0, Wt1, Wt2, Wt3);

  int gblocks = (NODES + 63)/64;
  int mblocks = (NGRP + 3)/4;
  int ablocks = (NODES + 3)/4;

  // layer 0 GEMM: y0 = f2b(feats)@W0  (f32 input, in-register conversion)
  gemm_k<8, true><<<gblocks, 256, 0, stream>>>(feats, Wt0, yb, NODES);
  // fused: h1 = relu((1+e0)y0 + mean(y0) + b0); y1 = h1@W1   (yb -> hb)
  fagg_k<8><<<mblocks, 256, 0, stream>>>(yb, elist, offs, invd, b0, eps, 0, Wt1, hb);
  // fused: h2 = relu((1+e1)y1 + mean(y1) + b1); y2 = h2@W2   (hb -> yb)
  fagg_k<8><<<mblocks, 256, 0, stream>>>(hb, elist, offs, invd, b1, eps, 1, Wt2, yb);
  // fused: h3 = relu((1+e2)y2 + mean(y2) + b2); y3 = h3@W3   (yb -> hb, 16 cols)
  fagg_k<1><<<mblocks, 256, 0, stream>>>(yb, elist, offs, invd, b2, eps, 2, Wt3, hb);
  // layer 3 epilogue: out = (1+e3)y3 + mean(y3) + b3  (f32, no relu)
  aggF2_k<<<ablocks, 256, 0, stream>>>(hb, elist, offs, degs, invd, b3, eps, (float*)d_out, NODES);
}